// Round 3
// baseline (110.871 us; speedup 1.0000x reference)
//
#include <hip/hip_runtime.h>
#include <hip/hip_bf16.h>

#define BH 16
#define L 2048
#define S 2048
#define DD 64
#define BMB 32               // L-rows per block
#define NPITCH 68            // numLDS row pitch (floats): 68%32=4 -> 2-way max
#define LDSPAD 8
#define LDW (DD + LDSPAD)

typedef __attribute__((ext_vector_type(4))) float f32x4;
typedef __bf16 bf16x8 __attribute__((ext_vector_type(8)));

union FragU {
  bf16x8 f;
  __hip_bfloat162 h2[4];
};

__device__ inline __hip_bfloat162 exp2pack(float al2, float nsl2, float k0,
                                           float k1, float& d) {
  float e0 = __builtin_amdgcn_exp2f(fmaf(al2, k0, nsl2));
  float e1 = __builtin_amdgcn_exp2f(fmaf(al2, k1, nsl2));
  d += e0 + e1;
  return __float22bfloat162_rn(make_float2(e0, e1));
}

// ---------------------------------------------------------------------------
// prep: blocks [0,2048): K row sums (16 lanes per row).
//       blocks [2048,2560): V [bh][s][d] fp32 -> VT [bh][d][s] bf16 transpose.
// ---------------------------------------------------------------------------
__global__ __launch_bounds__(256) void prep_kernel(
    const float* __restrict__ k, const float* __restrict__ v,
    float* __restrict__ ks, __hip_bfloat16* __restrict__ vt) {
  __shared__ __hip_bfloat16 tile[DD][LDW];
  int t = threadIdx.x;
  if (blockIdx.x < 2048) {
    int g = blockIdx.x * 256 + t;
    int row = g >> 4;
    int l16 = g & 15;
    float4 x = reinterpret_cast<const float4*>(k + (size_t)row * DD)[l16];
    float s = x.x + x.y + x.z + x.w;
    s += __shfl_xor(s, 1);
    s += __shfl_xor(s, 2);
    s += __shfl_xor(s, 4);
    s += __shfl_xor(s, 8);
    if (l16 == 0) ks[row] = s;
  } else {
    int bid = blockIdx.x - 2048;
    int s0 = (bid & 31) * 64;
    int bh = bid >> 5;
    int srow = t >> 4;
    int d4 = (t & 15) * 4;
#pragma unroll
    for (int kk = 0; kk < 4; ++kk) {
      int s = srow + kk * 16;
      float4 val = *reinterpret_cast<const float4*>(
          v + ((size_t)(bh * S + s0 + s)) * DD + d4);
      tile[d4 + 0][s] = __float2bfloat16(val.x);
      tile[d4 + 1][s] = __float2bfloat16(val.y);
      tile[d4 + 2][s] = __float2bfloat16(val.z);
      tile[d4 + 3][s] = __float2bfloat16(val.w);
    }
    __syncthreads();
    int dd = t >> 3;
    int j = t & 7;
#pragma unroll
    for (int kk = 0; kk < 2; ++kk) {
      int d = dd + kk * 32;
      uint4 val = *reinterpret_cast<const uint4*>(&tile[d][j * 8]);
      *reinterpret_cast<uint4*>(vt + ((size_t)(bh * DD + d)) * S + s0 + j * 8) =
          val;
    }
  }
}

// ---------------------------------------------------------------------------
// attn: block = 32 L-rows of one head; wave w handles S-quarter [w*512,
// (w+1)*512). K-loop is BARRIER-FREE and LDS-FREE: E generated per-lane in
// A-fragment registers, B-fragments loaded directly from global VT (L2-hot).
// Partial numerators/denominators are additive across waves (same per-head
// sel); combined once through LDS in the epilogue.
// ---------------------------------------------------------------------------
__global__ __launch_bounds__(256, 4) void attn_kernel(
    const float* __restrict__ q, const __hip_bfloat16* __restrict__ vt,
    const float* __restrict__ ks, float* __restrict__ out) {
  int l0 = blockIdx.x * BMB;
  int bh = blockIdx.y;

  __shared__ float numLDS[4][BMB][NPITCH];
  __shared__ float dLDS[4][BMB];
  __shared__ float a_row[BMB];
  __shared__ float red[16];

  int t = threadIdx.x;
  int lane = t & 63;
  int w = t >> 6;
  int m = lane & 15;
  int qd = lane >> 4;

  const float* ksb = ks + (size_t)bh * S;
  const __hip_bfloat16* vtb = vt + (size_t)bh * DD * S;

  // --- qsum for this block's 32 rows: 8 lanes per row
  {
    int r = t >> 3;
    int p = t & 7;
    const float* qp = q + ((size_t)(bh * L + l0 + r)) * DD + p * 8;
    float4 x0 = reinterpret_cast<const float4*>(qp)[0];
    float4 x1 = reinterpret_cast<const float4*>(qp)[1];
    float s = (x0.x + x0.y + x0.z + x0.w) + (x1.x + x1.y + x1.z + x1.w);
    s += __shfl_xor(s, 1);
    s += __shfl_xor(s, 2);
    s += __shfl_xor(s, 4);
    if (p == 0) a_row[r] = s;
  }
  // --- per-head kmax/kmin (each block computes identically -> consistent sel)
  {
    const float* kp = ksb + t * 8;
    float4 y0 = reinterpret_cast<const float4*>(kp)[0];
    float4 y1 = reinterpret_cast<const float4*>(kp)[1];
    float mx = fmaxf(fmaxf(fmaxf(y0.x, y0.y), fmaxf(y0.z, y0.w)),
                     fmaxf(fmaxf(y1.x, y1.y), fmaxf(y1.z, y1.w)));
    float mn = fminf(fminf(fminf(y0.x, y0.y), fminf(y0.z, y0.w)),
                     fminf(fminf(y1.x, y1.y), fminf(y1.z, y1.w)));
#pragma unroll
    for (int off = 1; off < 64; off <<= 1) {
      mx = fmaxf(mx, __shfl_xor(mx, off));
      mn = fminf(mn, __shfl_xor(mn, off));
    }
    if (lane == 0) {
      red[w] = mx;
      red[8 + w] = mn;
    }
  }
  __syncthreads();

  float kmax = fmaxf(fmaxf(red[0], red[1]), fmaxf(red[2], red[3]));
  float kmin = fminf(fminf(red[8], red[9]), fminf(red[10], red[11]));
  const float LOG2E = 1.44269504088896f;
  float ar0 = a_row[m];       // A-frag rows 0..15
  float ar1 = a_row[16 + m];  // A-frag rows 16..31
  float al20 = ar0 * LOG2E, al21 = ar1 * LOG2E;
  float nsl20 = -al20 * ((ar0 > 0.f) ? kmax : kmin);
  float nsl21 = -al21 * ((ar1 > 0.f) ? kmax : kmin);

  f32x4 acc[2][4];
#pragma unroll
  for (int a = 0; a < 2; ++a)
#pragma unroll
    for (int c = 0; c < 4; ++c) acc[a][c] = (f32x4){0.f, 0.f, 0.f, 0.f};
  float ds0a = 0.f, ds0b = 0.f, ds1a = 0.f, ds1b = 0.f;

  // B-row base pointers for the 4 column groups (d = c*16 + m)
  const __hip_bfloat16* bp0 = vtb + (size_t)(0 * 16 + m) * S + qd * 8;
  const __hip_bfloat16* bp1 = vtb + (size_t)(1 * 16 + m) * S + qd * 8;
  const __hip_bfloat16* bp2 = vtb + (size_t)(2 * 16 + m) * S + qd * 8;
  const __hip_bfloat16* bp3 = vtb + (size_t)(3 * 16 + m) * S + qd * 8;

  int sw = w * (S / 4);
  for (int it = 0; it < (S / 4) / 64; ++it) {
    int sb = sw + it * 64;
    // ksum values for this lane's 16 k-slots (shared by both A-row-tiles)
    float4 kA0 = *reinterpret_cast<const float4*>(ksb + sb + qd * 8);
    float4 kA1 = *reinterpret_cast<const float4*>(ksb + sb + qd * 8 + 4);
    float4 kB0 = *reinterpret_cast<const float4*>(ksb + sb + 32 + qd * 8);
    float4 kB1 = *reinterpret_cast<const float4*>(ksb + sb + 32 + qd * 8 + 4);
    // B-fragments straight from global (L2-hot VT)
    uint4 b00 = *reinterpret_cast<const uint4*>(bp0 + sb);
    uint4 b01 = *reinterpret_cast<const uint4*>(bp1 + sb);
    uint4 b02 = *reinterpret_cast<const uint4*>(bp2 + sb);
    uint4 b03 = *reinterpret_cast<const uint4*>(bp3 + sb);
    uint4 b10 = *reinterpret_cast<const uint4*>(bp0 + sb + 32);
    uint4 b11 = *reinterpret_cast<const uint4*>(bp1 + sb + 32);
    uint4 b12 = *reinterpret_cast<const uint4*>(bp2 + sb + 32);
    uint4 b13 = *reinterpret_cast<const uint4*>(bp3 + sb + 32);

    FragU e00, e01, e10, e11;  // [row-tile][k-half]
    e00.h2[0] = exp2pack(al20, nsl20, kA0.x, kA0.y, ds0a);
    e00.h2[1] = exp2pack(al20, nsl20, kA0.z, kA0.w, ds0a);
    e00.h2[2] = exp2pack(al20, nsl20, kA1.x, kA1.y, ds0a);
    e00.h2[3] = exp2pack(al20, nsl20, kA1.z, kA1.w, ds0a);
    e01.h2[0] = exp2pack(al20, nsl20, kB0.x, kB0.y, ds0b);
    e01.h2[1] = exp2pack(al20, nsl20, kB0.z, kB0.w, ds0b);
    e01.h2[2] = exp2pack(al20, nsl20, kB1.x, kB1.y, ds0b);
    e01.h2[3] = exp2pack(al20, nsl20, kB1.z, kB1.w, ds0b);
    e10.h2[0] = exp2pack(al21, nsl21, kA0.x, kA0.y, ds1a);
    e10.h2[1] = exp2pack(al21, nsl21, kA0.z, kA0.w, ds1a);
    e10.h2[2] = exp2pack(al21, nsl21, kA1.x, kA1.y, ds1a);
    e10.h2[3] = exp2pack(al21, nsl21, kA1.z, kA1.w, ds1a);
    e11.h2[0] = exp2pack(al21, nsl21, kB0.x, kB0.y, ds1b);
    e11.h2[1] = exp2pack(al21, nsl21, kB0.z, kB0.w, ds1b);
    e11.h2[2] = exp2pack(al21, nsl21, kB1.x, kB1.y, ds1b);
    e11.h2[3] = exp2pack(al21, nsl21, kB1.z, kB1.w, ds1b);

    acc[0][0] = __builtin_amdgcn_mfma_f32_16x16x32_bf16(
        e00.f, __builtin_bit_cast(bf16x8, b00), acc[0][0], 0, 0, 0);
    acc[0][1] = __builtin_amdgcn_mfma_f32_16x16x32_bf16(
        e00.f, __builtin_bit_cast(bf16x8, b01), acc[0][1], 0, 0, 0);
    acc[0][2] = __builtin_amdgcn_mfma_f32_16x16x32_bf16(
        e00.f, __builtin_bit_cast(bf16x8, b02), acc[0][2], 0, 0, 0);
    acc[0][3] = __builtin_amdgcn_mfma_f32_16x16x32_bf16(
        e00.f, __builtin_bit_cast(bf16x8, b03), acc[0][3], 0, 0, 0);
    acc[1][0] = __builtin_amdgcn_mfma_f32_16x16x32_bf16(
        e10.f, __builtin_bit_cast(bf16x8, b00), acc[1][0], 0, 0, 0);
    acc[1][1] = __builtin_amdgcn_mfma_f32_16x16x32_bf16(
        e10.f, __builtin_bit_cast(bf16x8, b01), acc[1][1], 0, 0, 0);
    acc[1][2] = __builtin_amdgcn_mfma_f32_16x16x32_bf16(
        e10.f, __builtin_bit_cast(bf16x8, b02), acc[1][2], 0, 0, 0);
    acc[1][3] = __builtin_amdgcn_mfma_f32_16x16x32_bf16(
        e10.f, __builtin_bit_cast(bf16x8, b03), acc[1][3], 0, 0, 0);
    acc[0][0] = __builtin_amdgcn_mfma_f32_16x16x32_bf16(
        e01.f, __builtin_bit_cast(bf16x8, b10), acc[0][0], 0, 0, 0);
    acc[0][1] = __builtin_amdgcn_mfma_f32_16x16x32_bf16(
        e01.f, __builtin_bit_cast(bf16x8, b11), acc[0][1], 0, 0, 0);
    acc[0][2] = __builtin_amdgcn_mfma_f32_16x16x32_bf16(
        e01.f, __builtin_bit_cast(bf16x8, b12), acc[0][2], 0, 0, 0);
    acc[0][3] = __builtin_amdgcn_mfma_f32_16x16x32_bf16(
        e01.f, __builtin_bit_cast(bf16x8, b13), acc[0][3], 0, 0, 0);
    acc[1][0] = __builtin_amdgcn_mfma_f32_16x16x32_bf16(
        e11.f, __builtin_bit_cast(bf16x8, b10), acc[1][0], 0, 0, 0);
    acc[1][1] = __builtin_amdgcn_mfma_f32_16x16x32_bf16(
        e11.f, __builtin_bit_cast(bf16x8, b11), acc[1][1], 0, 0, 0);
    acc[1][2] = __builtin_amdgcn_mfma_f32_16x16x32_bf16(
        e11.f, __builtin_bit_cast(bf16x8, b12), acc[1][2], 0, 0, 0);
    acc[1][3] = __builtin_amdgcn_mfma_f32_16x16x32_bf16(
        e11.f, __builtin_bit_cast(bf16x8, b13), acc[1][3], 0, 0, 0);
  }

  // per-wave row denominators (lanes m, m+16, m+32, m+48 share a row)
  float ds0 = ds0a + ds0b;
  float ds1 = ds1a + ds1b;
  ds0 += __shfl_xor(ds0, 16);
  ds0 += __shfl_xor(ds0, 32);
  ds1 += __shfl_xor(ds1, 16);
  ds1 += __shfl_xor(ds1, 32);
  if (qd == 0) {
    dLDS[w][m] = ds0;
    dLDS[w][16 + m] = ds1;
  }
  // per-wave partial numerators (C layout: col=lane&15, row=quad*4+reg)
#pragma unroll
  for (int a = 0; a < 2; ++a)
#pragma unroll
    for (int c = 0; c < 4; ++c)
#pragma unroll
      for (int i = 0; i < 4; ++i)
        numLDS[w][a * 16 + qd * 4 + i][c * 16 + m] = acc[a][c][i];
  __syncthreads();

  // combine 4 waves + normalize + coalesced store
  {
    int r = t >> 3;
    int cg = (t & 7) * 8;
    float4 n0 = *reinterpret_cast<const float4*>(&numLDS[0][r][cg]);
    float4 n1 = *reinterpret_cast<const float4*>(&numLDS[0][r][cg + 4]);
#pragma unroll
    for (int ww = 1; ww < 4; ++ww) {
      float4 p0 = *reinterpret_cast<const float4*>(&numLDS[ww][r][cg]);
      float4 p1 = *reinterpret_cast<const float4*>(&numLDS[ww][r][cg + 4]);
      n0.x += p0.x; n0.y += p0.y; n0.z += p0.z; n0.w += p0.w;
      n1.x += p1.x; n1.y += p1.y; n1.z += p1.z; n1.w += p1.w;
    }
    float inv = 1.0f / (dLDS[0][r] + dLDS[1][r] + dLDS[2][r] + dLDS[3][r]);
    n0.x *= inv; n0.y *= inv; n0.z *= inv; n0.w *= inv;
    n1.x *= inv; n1.y *= inv; n1.z *= inv; n1.w *= inv;
    float* ob = out + ((size_t)(bh * L + l0 + r)) * DD + cg;
    reinterpret_cast<float4*>(ob)[0] = n0;
    reinterpret_cast<float4*>(ob)[1] = n1;
  }
}

extern "C" void kernel_launch(void* const* d_in, const int* in_sizes, int n_in,
                              void* d_out, int out_size, void* d_ws,
                              size_t ws_size, hipStream_t stream) {
  const float* q = (const float*)d_in[0];
  const float* k = (const float*)d_in[1];
  const float* v = (const float*)d_in[2];
  float* out = (float*)d_out;
  float* ws = (float*)d_ws;

  float* ks = ws;  // BH*S = 32768 floats
  __hip_bfloat16* vt = (__hip_bfloat16*)(ws + BH * S);  // BH*DD*S bf16 = 4MB

  prep_kernel<<<2048 + 512, 256, 0, stream>>>(k, v, ks, vt);
  attn_kernel<<<dim3(L / BMB, BH), 256, 0, stream>>>(q, vt, ks, out);
}